// Round 18
// baseline (112.700 us; speedup 1.0000x reference)
//
#include <hip/hip_runtime.h>
#include <hip/hip_bf16.h>

// ---- problem constants -------------------------------------------------
#define IN_F   1024
#define OUT_F  1024
#define GS     5          // grid_size
#define SO     3          // spline_order
#define NB     (GS + SO)  // 8 basis functions per feature
#define NG     (GS + 2*SO + 1) // 12 grid points per feature row
#define BATCH  4096
#define KC     (IN_F + IN_F * NB)   // 9216 combined-K
#define BM 256
#define BN 256
#define BK 64
#define SPLITK 4
#define KPART  (KC / SPLITK)   // 2304
#define NT     (KPART / BK)    // 36 K-tiles per block

typedef __bf16 bf16x8 __attribute__((ext_vector_type(8)));
typedef float  f32x4  __attribute__((ext_vector_type(4)));

__device__ __forceinline__ void gload_lds16(const void* g, void* l) {
    __builtin_amdgcn_global_load_lds(
        (const __attribute__((address_space(1))) void*)g,
        (__attribute__((address_space(3))) void*)l,
        16, 0, 0);
}

// ---- fused prep: blocks [0,WC_BLK) build Wc, rest build A ---------------
#define WC_BLK 4608   // (131072 + 1048576) / 256
#define A_BLK  18432  // (524288 + 4194304) / 256

__global__ __launch_bounds__(256) void prep_all(const float* __restrict__ bw,
                                                const float* __restrict__ sw,
                                                const float* __restrict__ ss,
                                                const float* __restrict__ x,
                                                __bf16* __restrict__ W,
                                                __bf16* __restrict__ A) {
    if (blockIdx.x < WC_BLK) {
        const int t = blockIdx.x * 256 + threadIdx.x;
        const int NBASE = OUT_F * IN_F / 8;      // 131072 threads, 8 elems each
        if (t < NBASE) {
            const int o  = t >> 7;
            const int c8 = (t & 127) * 8;
            const float4* sp = (const float4*)(bw + (size_t)o * IN_F + c8);
            float4 v0 = sp[0], v1 = sp[1];
            float v[8] = {v0.x, v0.y, v0.z, v0.w, v1.x, v1.y, v1.z, v1.w};
            bf16x8 ov;
#pragma unroll
            for (int j = 0; j < 8; ++j) ov[j] = (__bf16)v[j];
            *(bf16x8*)(W + (size_t)o * KC + c8) = ov;
        } else {
            const int u = t - NBASE;             // one (o,f) pair per thread
            if (u >= OUT_F * IN_F) return;
            const int o = u >> 10, f = u & 1023;
            const float s = ss[(size_t)o * IN_F + f];
            const float4* sp = (const float4*)(sw + ((size_t)o * IN_F + f) * NB);
            float4 v0 = sp[0], v1 = sp[1];
            float v[8] = {v0.x, v0.y, v0.z, v0.w, v1.x, v1.y, v1.z, v1.w};
            bf16x8 ov;
#pragma unroll
            for (int j = 0; j < 8; ++j) ov[j] = (__bf16)(v[j] * s);
            *(bf16x8*)(W + (size_t)o * KC + IN_F + (size_t)f * NB) = ov;
        }
    } else {
        const int t = (blockIdx.x - WC_BLK) * 256 + threadIdx.x;
        const int NBASE = BATCH * IN_F / 8;      // silu: 8 elems/thread
        if (t < NBASE) {
            const int b  = t >> 7;
            const int c8 = (t & 127) * 8;
            const float4* sp = (const float4*)(x + (size_t)b * IN_F + c8);
            float4 v0 = sp[0], v1 = sp[1];
            float v[8] = {v0.x, v0.y, v0.z, v0.w, v1.x, v1.y, v1.z, v1.w};
            bf16x8 ov;
#pragma unroll
            for (int j = 0; j < 8; ++j) {
                float xx = v[j];
                ov[j] = (__bf16)(xx / (1.0f + __expf(-xx)));
            }
            *(bf16x8*)(A + (size_t)b * KC + c8) = ov;
        } else {
            const int u = t - NBASE;             // one (b,f) pair per thread
            if (u >= BATCH * IN_F) return;
            const int b = u >> 10, f = u & 1023;
            const float xv = x[(size_t)b * IN_F + f];
            const float h = 2.0f / GS;           // 0.4; uniform grid
            float gv[NG];
#pragma unroll
            for (int j = 0; j < NG; ++j) gv[j] = (float)(j - SO) * h - 1.0f;
            float bas[NB + SO];                  // 11 order-0 bases
#pragma unroll
            for (int j = 0; j < NB + SO; ++j)
                bas[j] = (xv >= gv[j] && xv < gv[j + 1]) ? 1.0f : 0.0f;
#pragma unroll
            for (int k = 1; k <= SO; ++k) {
                const float rk = 1.0f / ((float)k * h);   // constant-folded
#pragma unroll
                for (int j = 0; j <= (NB + SO - 1) - k; ++j) {
                    float left  = (xv - gv[j]) * rk;
                    float right = (gv[j + k + 1] - xv) * rk;
                    bas[j] = left * bas[j] + right * bas[j + 1];
                }
            }
            bf16x8 ov;
#pragma unroll
            for (int i = 0; i < NB; ++i) ov[i] = (__bf16)bas[i];
            *(bf16x8*)(A + (size_t)b * KC + IN_F + (size_t)f * NB) = ov;
        }
    }
}

// ---- zero-fill d_out (atomic-fallback path only) -----------------------
__global__ __launch_bounds__(256) void zero_out(float4* __restrict__ p, int n4) {
    const int i = blockIdx.x * 256 + threadIdx.x;
    if (i < n4) p[i] = float4{0.f, 0.f, 0.f, 0.f};
}

// ---- sum bf16 split-K partials into fp32 d_out (ks=0 wrote C) ----------
__global__ __launch_bounds__(256) void reduce_k(float4* __restrict__ C4,
                                                const __bf16* __restrict__ P) {
    const size_t n8 = (size_t)BATCH * OUT_F / 8;   // 524,288 groups of 8
    const bf16x8* P8 = (const bf16x8*)P;
    for (size_t i = blockIdx.x * 256 + threadIdx.x; i < n8; i += 2048 * 256) {
        float4 c0 = C4[2 * i], c1 = C4[2 * i + 1];
        bf16x8 p0 = P8[i];
        bf16x8 p1 = P8[n8 + i];
        bf16x8 p2 = P8[2 * n8 + i];
        c0.x += (float)p0[0] + (float)p1[0] + (float)p2[0];
        c0.y += (float)p0[1] + (float)p1[1] + (float)p2[1];
        c0.z += (float)p0[2] + (float)p1[2] + (float)p2[2];
        c0.w += (float)p0[3] + (float)p1[3] + (float)p2[3];
        c1.x += (float)p0[4] + (float)p1[4] + (float)p2[4];
        c1.y += (float)p0[5] + (float)p1[5] + (float)p2[5];
        c1.z += (float)p0[6] + (float)p1[6] + (float)p2[6];
        c1.w += (float)p0[7] + (float)p1[7] + (float)p2[7];
        C4[2 * i] = c0; C4[2 * i + 1] = c1;
    }
}

// ---- 256x256 GEMM: r18 = r17 with SINGLE mid-tile barrier --------------
// Barrier audit: Ph2/Ph3 barriers each protected the next phase's stage.
// Consolidate: one fence(0)+barrier at Ph3 (all 24 tile reads retired
// block-wide), then ALL stages (B1(t+1), B0(t+2), A(t+2)) issue together.
// vmcnt ledger: 8 stage-loads/tile at Ph3; boundary vmcnt(6) retires
// exactly B1(t+1) (oldest 2 of 8); prologue leaves A(1)+B0(1)=6; tile-0
// boundary retires A(1),B0(1),B1(1); tail vmcnt(0). Barriers 3->2/tile.
#define MFMAQ(AF, BF, MI0, NI0)                                               \
    __builtin_amdgcn_s_setprio(1);                                            \
    _Pragma("unroll")                                                         \
    for (int kk_ = 0; kk_ < 2; ++kk_)                                         \
        _Pragma("unroll")                                                     \
        for (int i_ = 0; i_ < 4; ++i_)                                        \
            _Pragma("unroll")                                                 \
            for (int n_ = 0; n_ < 2; ++n_)                                    \
                acc[(MI0) + i_][(NI0) + n_] =                                 \
                    __builtin_amdgcn_mfma_f32_16x16x32_bf16(                  \
                        AF[i_][kk_], BF[n_][kk_],                             \
                        acc[(MI0) + i_][(NI0) + n_], 0, 0, 0);                \
    __builtin_amdgcn_s_setprio(0);

#define RD_A4(DST, LBUF, MI0)                                                 \
    _Pragma("unroll")                                                         \
    for (int i_ = 0; i_ < 4; ++i_) {                                          \
        DST[i_][0] = *(const bf16x8*)&(LBUF)[((MI0) + i_) * 1024 + aRow + slot0]; \
        DST[i_][1] = *(const bf16x8*)&(LBUF)[((MI0) + i_) * 1024 + aRow + slot1]; \
    }

#define RD_B2(DST, LBUF, NI0)                                                 \
    _Pragma("unroll")                                                         \
    for (int n_ = 0; n_ < 2; ++n_) {                                          \
        DST[n_][0] = *(const bf16x8*)&(LBUF)[bRow + ((NI0) + n_) * 1024 + slot0]; \
        DST[n_][1] = *(const bf16x8*)&(LBUF)[bRow + ((NI0) + n_) * 1024 + slot1]; \
    }

#define LGKM_FENCE(N)                                                         \
    asm volatile("s_waitcnt lgkmcnt(" #N ")" ::: "memory");                   \
    __builtin_amdgcn_sched_barrier(0)

template<bool ATOMIC>
__global__ __launch_bounds__(512, 2) void kan_gemm(const __bf16* __restrict__ A,
                                                   const __bf16* __restrict__ W,
                                                   float* __restrict__ C,
                                                   __bf16* __restrict__ P) {
    __shared__ __bf16 sA[2][2][128 * BK];   // [buf][half][128x64] = 64 KiB
    __shared__ __bf16 sB[2][2][128 * BK];   // 64 KiB

    const int tid  = threadIdx.x;
    const int gid  = blockIdx.x;
    // bijective XCD swizzle (256 = 8*32): XCD x owns one ks, two bn panels.
    const int work = (gid & 7) * 32 + (gid >> 3);
    const int ks = work >> 6;          // 0..3
    const int bn = (work >> 4) & 3;    // 0..3
    const int bm = work & 15;          // 0..15

    const int lane = tid & 63;
    const int wv   = tid >> 6;         // 0..7
    const int wm   = wv >> 2;          // 0..1: A half
    const int wn   = wv & 3;           // 0..3: B half = wn>>1, sub = wn&1
    const int lr   = lane & 15;        // fragment row
    const int hi   = lane >> 4;        // 0..3: k-subslot
    const int key  = lr & 7;           // swizzle key (frag rows = 16*m + lr)

    const int slot0 = ((hi ^ key) << 3);        // kk=0: 16B slot 0..3
    const int slot1 = (((4 + hi) ^ key) << 3);  // kk=1: slot 4..7
    const int aRow  = lr * 64;                  // within sA[b][wm]
    const int bRow  = ((wn & 1) * 64 + lr) * 64;// within sB[b][wn>>1]

    // staging map: thread -> (row, swizzled col) for each half-tile
    const int srow = tid >> 3;                       // 0..63
    const int scol = ((tid & 7) ^ (srow & 7)) << 3;  // elems

    const __bf16* gA = A + (size_t)(bm * BM) * KC + ks * KPART;
    const __bf16* gW = W + (size_t)(bn * BN) * KC + ks * KPART;

    f32x4 acc[8][4] = {};
    bf16x8 a0[4][2], a1[4][2], b01[2][2], b23[2][2];

    auto stageA = [&](int buf, int h, int kt) {      // one 16 KiB half-tile
#pragma unroll
        for (int l = 0; l < 2; ++l)
            gload_lds16(gA + (size_t)(h * 128 + l * 64 + srow) * KC + kt * BK + scol,
                        &sA[buf][h][(l * 512 + tid) * 8]);
    };
    auto stageB = [&](int buf, int h, int kt) {
#pragma unroll
        for (int l = 0; l < 2; ++l)
            gload_lds16(gW + (size_t)(h * 128 + l * 64 + srow) * KC + kt * BK + scol,
                        &sB[buf][h][(l * 512 + tid) * 8]);
    };

    // prologue: tile0 fully (8 loads) + tile1 A0,A1,B0 (6 loads)
    stageA(0, 0, 0); stageA(0, 1, 0); stageB(0, 0, 0); stageB(0, 1, 0);
    stageA(1, 0, 1); stageA(1, 1, 1); stageB(1, 0, 1);
    asm volatile("s_waitcnt vmcnt(6)\n\ts_barrier" ::: "memory");

    for (int kt = 0; kt < NT; ++kt) {
        const int b = kt & 1;
        const __bf16* LA = &sA[b][wm][0];
        const __bf16* LB = &sB[b][wn >> 1][0];

        // ---- entry: issue a0 (8) + b01 (4)
        RD_A4(a0, LA, 0);
        RD_B2(b01, LB, 0);
        __builtin_amdgcn_sched_barrier(0);   // pin issue order for counts

        // ---- Ph1: issue b23 (4); fence(4) retires entry; Q1 = a0*b01
        RD_B2(b23, LB, 2);
        LGKM_FENCE(4);
        MFMAQ(a0, b01, 0, 0);

        // ---- Ph2: issue a1 (8); fence(8) retires b23 (drained under Q1);
        //      Q2 = a0*b23  (no barrier here anymore)
        RD_A4(a1, LA, 4);
        LGKM_FENCE(8);
        MFMAQ(a0, b23, 0, 2);

        // ---- Ph3: fence(0) retires a1 (drained under Q2); ONE barrier
        //      (all 24 reads of buf b retired block-wide); then ALL stages:
        //      B1(t+1), B0(t+2), A(t+2); Q3 = a1*b01
        LGKM_FENCE(0);
        __builtin_amdgcn_s_barrier();
        if (kt + 1 < NT) stageB(b ^ 1, 1, kt + 1);
        if (kt + 2 < NT) { stageB(b, 0, kt + 2); stageA(b, 0, kt + 2); stageA(b, 1, kt + 2); }
        MFMAQ(a1, b01, 4, 0);

        // ---- Ph4: Q4 = a1*b23 (reg-only)
        MFMAQ(a1, b23, 4, 2);

        // ---- boundary: counted wait; retires exactly B1(t+1)
        if (kt + 2 < NT)
            asm volatile("s_waitcnt vmcnt(6)\n\ts_barrier" ::: "memory");
        else if (kt + 1 < NT)
            asm volatile("s_waitcnt vmcnt(0)\n\ts_barrier" ::: "memory");
    }

    // epilogue: C/D layout col=lane&15, row=hi*4+reg
    const int cr = hi * 4, cc = lane & 15;
    if (ATOMIC) {
#pragma unroll
        for (int mi = 0; mi < 8; ++mi)
#pragma unroll
            for (int ni = 0; ni < 4; ++ni) {
                float* cp = C + (size_t)(bm * BM + wm * 128 + mi * 16 + cr) * OUT_F
                              + bn * BN + wn * 64 + ni * 16 + cc;
#pragma unroll
                for (int r = 0; r < 4; ++r)
                    unsafeAtomicAdd(cp + (size_t)r * OUT_F, acc[mi][ni][r]);
            }
    } else if (ks == 0) {
#pragma unroll
        for (int mi = 0; mi < 8; ++mi)
#pragma unroll
            for (int ni = 0; ni < 4; ++ni) {
                float* cp = C + (size_t)(bm * BM + wm * 128 + mi * 16 + cr) * OUT_F
                              + bn * BN + wn * 64 + ni * 16 + cc;
#pragma unroll
                for (int r = 0; r < 4; ++r)
                    cp[(size_t)r * OUT_F] = acc[mi][ni][r];
            }
    } else {
        __bf16* pp = P + (size_t)(ks - 1) * BATCH * OUT_F;
#pragma unroll
        for (int mi = 0; mi < 8; ++mi)
#pragma unroll
            for (int ni = 0; ni < 4; ++ni) {
                __bf16* cp = pp + (size_t)(bm * BM + wm * 128 + mi * 16 + cr) * OUT_F
                                + bn * BN + wn * 64 + ni * 16 + cc;
#pragma unroll
                for (int r = 0; r < 4; ++r)
                    cp[(size_t)r * OUT_F] = (__bf16)acc[mi][ni][r];
            }
    }
}

extern "C" void kernel_launch(void* const* d_in, const int* in_sizes, int n_in,
                              void* d_out, int out_size, void* d_ws, size_t ws_size,
                              hipStream_t stream) {
    const float* x    = (const float*)d_in[0];
    const float* bw   = (const float*)d_in[1];
    const float* sw   = (const float*)d_in[2];
    const float* ss   = (const float*)d_in[3];

    const size_t wc_bytes   = (size_t)OUT_F * KC * 2;          // 18,874,368
    const size_t a_bytes    = (size_t)BATCH * KC * 2;          // 75,497,472
    const size_t part_bytes = 3ull * BATCH * OUT_F * 2;        // 25,165,824 (bf16)
    if (ws_size < wc_bytes + a_bytes) return;

    __bf16* Wc = (__bf16*)d_ws;
    __bf16* A  = (__bf16*)((char*)d_ws + wc_bytes);
    __bf16* P  = (__bf16*)((char*)d_ws + wc_bytes + a_bytes);

    prep_all<<<WC_BLK + A_BLK, 256, 0, stream>>>(bw, sw, ss, x, Wc, A);

    const int grid = (BATCH / BM) * (OUT_F / BN) * SPLITK;     // 256
    if (ws_size >= wc_bytes + a_bytes + part_bytes) {
        kan_gemm<false><<<grid, 512, 0, stream>>>(A, Wc, (float*)d_out, P);
        reduce_k<<<2048, 256, 0, stream>>>((float4*)d_out, (const __bf16*)P);
    } else {
        const int n4 = BATCH * OUT_F / 4;
        zero_out<<<n4 / 256, 256, 0, stream>>>((float4*)d_out, n4);
        kan_gemm<true><<<grid, 512, 0, stream>>>(A, Wc, (float*)d_out, P);
    }
}

// Round 19
// 106.653 us; speedup vs baseline: 1.0567x; 1.0567x over previous
//
#include <hip/hip_runtime.h>
#include <hip/hip_bf16.h>

// ---- problem constants -------------------------------------------------
#define IN_F   1024
#define OUT_F  1024
#define GS     5          // grid_size
#define SO     3          // spline_order
#define NB     (GS + SO)  // 8 basis functions per feature
#define NG     (GS + 2*SO + 1) // 12 grid points per feature row
#define BATCH  4096
#define KC     (IN_F + IN_F * NB)   // 9216 combined-K
#define BM 256
#define BN 256
#define BK 64
#define SPLITK 4
#define KPART  (KC / SPLITK)   // 2304
#define NT     (KPART / BK)    // 36 K-tiles per block

typedef __bf16 bf16x8 __attribute__((ext_vector_type(8)));
typedef float  f32x4  __attribute__((ext_vector_type(4)));

__device__ __forceinline__ void gload_lds16(const void* g, void* l) {
    __builtin_amdgcn_global_load_lds(
        (const __attribute__((address_space(1))) void*)g,
        (__attribute__((address_space(3))) void*)l,
        16, 0, 0);
}

// ---- fused prep: blocks [0,WC_BLK) build Wc, rest build A ---------------
#define WC_BLK 4608   // (131072 + 1048576) / 256
#define A_BLK  18432  // (524288 + 4194304) / 256

__global__ __launch_bounds__(256) void prep_all(const float* __restrict__ bw,
                                                const float* __restrict__ sw,
                                                const float* __restrict__ ss,
                                                const float* __restrict__ x,
                                                __bf16* __restrict__ W,
                                                __bf16* __restrict__ A) {
    if (blockIdx.x < WC_BLK) {
        const int t = blockIdx.x * 256 + threadIdx.x;
        const int NBASE = OUT_F * IN_F / 8;      // 131072 threads, 8 elems each
        if (t < NBASE) {
            const int o  = t >> 7;
            const int c8 = (t & 127) * 8;
            const float4* sp = (const float4*)(bw + (size_t)o * IN_F + c8);
            float4 v0 = sp[0], v1 = sp[1];
            float v[8] = {v0.x, v0.y, v0.z, v0.w, v1.x, v1.y, v1.z, v1.w};
            bf16x8 ov;
#pragma unroll
            for (int j = 0; j < 8; ++j) ov[j] = (__bf16)v[j];
            *(bf16x8*)(W + (size_t)o * KC + c8) = ov;
        } else {
            const int u = t - NBASE;             // one (o,f) pair per thread
            if (u >= OUT_F * IN_F) return;
            const int o = u >> 10, f = u & 1023;
            const float s = ss[(size_t)o * IN_F + f];
            const float4* sp = (const float4*)(sw + ((size_t)o * IN_F + f) * NB);
            float4 v0 = sp[0], v1 = sp[1];
            float v[8] = {v0.x, v0.y, v0.z, v0.w, v1.x, v1.y, v1.z, v1.w};
            bf16x8 ov;
#pragma unroll
            for (int j = 0; j < 8; ++j) ov[j] = (__bf16)(v[j] * s);
            *(bf16x8*)(W + (size_t)o * KC + IN_F + (size_t)f * NB) = ov;
        }
    } else {
        const int t = (blockIdx.x - WC_BLK) * 256 + threadIdx.x;
        const int NBASE = BATCH * IN_F / 8;      // silu: 8 elems/thread
        if (t < NBASE) {
            const int b  = t >> 7;
            const int c8 = (t & 127) * 8;
            const float4* sp = (const float4*)(x + (size_t)b * IN_F + c8);
            float4 v0 = sp[0], v1 = sp[1];
            float v[8] = {v0.x, v0.y, v0.z, v0.w, v1.x, v1.y, v1.z, v1.w};
            bf16x8 ov;
#pragma unroll
            for (int j = 0; j < 8; ++j) {
                float xx = v[j];
                ov[j] = (__bf16)(xx / (1.0f + __expf(-xx)));
            }
            *(bf16x8*)(A + (size_t)b * KC + c8) = ov;
        } else {
            const int u = t - NBASE;             // one (b,f) pair per thread
            if (u >= BATCH * IN_F) return;
            const int b = u >> 10, f = u & 1023;
            const float xv = x[(size_t)b * IN_F + f];
            const float h = 2.0f / GS;           // 0.4; uniform grid
            float gv[NG];
#pragma unroll
            for (int j = 0; j < NG; ++j) gv[j] = (float)(j - SO) * h - 1.0f;
            float bas[NB + SO];                  // 11 order-0 bases
#pragma unroll
            for (int j = 0; j < NB + SO; ++j)
                bas[j] = (xv >= gv[j] && xv < gv[j + 1]) ? 1.0f : 0.0f;
#pragma unroll
            for (int k = 1; k <= SO; ++k) {
                const float rk = 1.0f / ((float)k * h);   // constant-folded
#pragma unroll
                for (int j = 0; j <= (NB + SO - 1) - k; ++j) {
                    float left  = (xv - gv[j]) * rk;
                    float right = (gv[j + k + 1] - xv) * rk;
                    bas[j] = left * bas[j] + right * bas[j + 1];
                }
            }
            bf16x8 ov;
#pragma unroll
            for (int i = 0; i < NB; ++i) ov[i] = (__bf16)bas[i];
            *(bf16x8*)(A + (size_t)b * KC + IN_F + (size_t)f * NB) = ov;
        }
    }
}

// ---- zero-fill d_out (atomic-fallback path only) -----------------------
__global__ __launch_bounds__(256) void zero_out(float4* __restrict__ p, int n4) {
    const int i = blockIdx.x * 256 + threadIdx.x;
    if (i < n4) p[i] = float4{0.f, 0.f, 0.f, 0.f};
}

// ---- sum 4 bf16 split-K partial slices -> fp32 d_out (write-only C) ----
__global__ __launch_bounds__(256) void reduce_k(float4* __restrict__ C4,
                                                const __bf16* __restrict__ P) {
    const size_t n8 = (size_t)BATCH * OUT_F / 8;   // 524,288 groups of 8
    const bf16x8* P8 = (const bf16x8*)P;
    for (size_t i = blockIdx.x * 256 + threadIdx.x; i < n8; i += 2048 * 256) {
        bf16x8 p0 = P8[i];
        bf16x8 p1 = P8[n8 + i];
        bf16x8 p2 = P8[2 * n8 + i];
        bf16x8 p3 = P8[3 * n8 + i];
        float4 c0, c1;
        c0.x = (float)p0[0] + (float)p1[0] + (float)p2[0] + (float)p3[0];
        c0.y = (float)p0[1] + (float)p1[1] + (float)p2[1] + (float)p3[1];
        c0.z = (float)p0[2] + (float)p1[2] + (float)p2[2] + (float)p3[2];
        c0.w = (float)p0[3] + (float)p1[3] + (float)p2[3] + (float)p3[3];
        c1.x = (float)p0[4] + (float)p1[4] + (float)p2[4] + (float)p3[4];
        c1.y = (float)p0[5] + (float)p1[5] + (float)p2[5] + (float)p3[5];
        c1.z = (float)p0[6] + (float)p1[6] + (float)p2[6] + (float)p3[6];
        c1.w = (float)p0[7] + (float)p1[7] + (float)p2[7] + (float)p3[7];
        C4[2 * i] = c0; C4[2 * i + 1] = c1;
    }
}

// ---- 256x256 GEMM: r17 K-loop (session best), all-bf16 partials --------
// r19 change: ALL 4 ks-slices store bf16 partials to P (GEMM WRITE
// 41.7->33.5 MB); reduce_k is write-only on C (57->49.5 MB). ks0 slice
// carries base_out (~0.9) -> bf16 RN error ~2e-3 abs, absmax ~1e-2 vs
// 2.94e-2 threshold.
#define MFMAQ(AF, BF, MI0, NI0)                                               \
    __builtin_amdgcn_s_setprio(1);                                            \
    _Pragma("unroll")                                                         \
    for (int kk_ = 0; kk_ < 2; ++kk_)                                         \
        _Pragma("unroll")                                                     \
        for (int i_ = 0; i_ < 4; ++i_)                                        \
            _Pragma("unroll")                                                 \
            for (int n_ = 0; n_ < 2; ++n_)                                    \
                acc[(MI0) + i_][(NI0) + n_] =                                 \
                    __builtin_amdgcn_mfma_f32_16x16x32_bf16(                  \
                        AF[i_][kk_], BF[n_][kk_],                             \
                        acc[(MI0) + i_][(NI0) + n_], 0, 0, 0);                \
    __builtin_amdgcn_s_setprio(0);

#define RD_A4(DST, LBUF, MI0)                                                 \
    _Pragma("unroll")                                                         \
    for (int i_ = 0; i_ < 4; ++i_) {                                          \
        DST[i_][0] = *(const bf16x8*)&(LBUF)[((MI0) + i_) * 1024 + aRow + slot0]; \
        DST[i_][1] = *(const bf16x8*)&(LBUF)[((MI0) + i_) * 1024 + aRow + slot1]; \
    }

#define RD_B2(DST, LBUF, NI0)                                                 \
    _Pragma("unroll")                                                         \
    for (int n_ = 0; n_ < 2; ++n_) {                                          \
        DST[n_][0] = *(const bf16x8*)&(LBUF)[bRow + ((NI0) + n_) * 1024 + slot0]; \
        DST[n_][1] = *(const bf16x8*)&(LBUF)[bRow + ((NI0) + n_) * 1024 + slot1]; \
    }

#define LGKM_FENCE(N)                                                         \
    asm volatile("s_waitcnt lgkmcnt(" #N ")" ::: "memory");                   \
    __builtin_amdgcn_sched_barrier(0)

template<bool ATOMIC>
__global__ __launch_bounds__(512, 2) void kan_gemm(const __bf16* __restrict__ A,
                                                   const __bf16* __restrict__ W,
                                                   float* __restrict__ C,
                                                   __bf16* __restrict__ P) {
    __shared__ __bf16 sA[2][2][128 * BK];   // [buf][half][128x64] = 64 KiB
    __shared__ __bf16 sB[2][2][128 * BK];   // 64 KiB

    const int tid  = threadIdx.x;
    const int gid  = blockIdx.x;
    // bijective XCD swizzle (256 = 8*32): XCD x owns one ks, two bn panels.
    const int work = (gid & 7) * 32 + (gid >> 3);
    const int ks = work >> 6;          // 0..3
    const int bn = (work >> 4) & 3;    // 0..3
    const int bm = work & 15;          // 0..15

    const int lane = tid & 63;
    const int wv   = tid >> 6;         // 0..7
    const int wm   = wv >> 2;          // 0..1: A half
    const int wn   = wv & 3;           // 0..3: B half = wn>>1, sub = wn&1
    const int lr   = lane & 15;        // fragment row
    const int hi   = lane >> 4;        // 0..3: k-subslot
    const int key  = lr & 7;           // swizzle key (frag rows = 16*m + lr)

    const int slot0 = ((hi ^ key) << 3);        // kk=0: 16B slot 0..3
    const int slot1 = (((4 + hi) ^ key) << 3);  // kk=1: slot 4..7
    const int aRow  = lr * 64;                  // within sA[b][wm]
    const int bRow  = ((wn & 1) * 64 + lr) * 64;// within sB[b][wn>>1]

    // staging map: thread -> (row, swizzled col) for each half-tile
    const int srow = tid >> 3;                       // 0..63
    const int scol = ((tid & 7) ^ (srow & 7)) << 3;  // elems

    const __bf16* gA = A + (size_t)(bm * BM) * KC + ks * KPART;
    const __bf16* gW = W + (size_t)(bn * BN) * KC + ks * KPART;

    f32x4 acc[8][4] = {};
    bf16x8 a0[4][2], a1[4][2], b01[2][2], b23[2][2];

    auto stageA = [&](int buf, int h, int kt) {      // one 16 KiB half-tile
#pragma unroll
        for (int l = 0; l < 2; ++l)
            gload_lds16(gA + (size_t)(h * 128 + l * 64 + srow) * KC + kt * BK + scol,
                        &sA[buf][h][(l * 512 + tid) * 8]);
    };
    auto stageB = [&](int buf, int h, int kt) {
#pragma unroll
        for (int l = 0; l < 2; ++l)
            gload_lds16(gW + (size_t)(h * 128 + l * 64 + srow) * KC + kt * BK + scol,
                        &sB[buf][h][(l * 512 + tid) * 8]);
    };

    // prologue: tile0 fully (8 loads) + tile1 A0,A1,B0 (6 loads)
    stageA(0, 0, 0); stageA(0, 1, 0); stageB(0, 0, 0); stageB(0, 1, 0);
    stageA(1, 0, 1); stageA(1, 1, 1); stageB(1, 0, 1);
    asm volatile("s_waitcnt vmcnt(6)\n\ts_barrier" ::: "memory");

    for (int kt = 0; kt < NT; ++kt) {
        const int b = kt & 1;
        const __bf16* LA = &sA[b][wm][0];
        const __bf16* LB = &sB[b][wn >> 1][0];

        // ---- entry: issue a0 (8) + b01 (4)
        RD_A4(a0, LA, 0);
        RD_B2(b01, LB, 0);
        __builtin_amdgcn_sched_barrier(0);   // pin issue order for counts

        // ---- Ph1: issue b23 (4); wait a0,b01; Q1 = a0*b01
        RD_B2(b23, LB, 2);
        LGKM_FENCE(4);
        MFMAQ(a0, b01, 0, 0);

        // ---- Ph2: issue a1 (8); stage (kt+1).B1; wait b23; B-WAR barrier;
        //      Q2 = a0*b23  (b23 drained under Q1)
        RD_A4(a1, LA, 4);
        if (kt + 1 < NT) stageB(b ^ 1, 1, kt + 1);
        LGKM_FENCE(8);
        __builtin_amdgcn_s_barrier();        // all waves' B-reads retired
        MFMAQ(a0, b23, 0, 2);

        // ---- Ph3: stage (kt+2).B0; wait a1 (drained under Q2);
        //      A-WAR barrier; Q3 = a1*b01
        if (kt + 2 < NT) stageB(b, 0, kt + 2);
        LGKM_FENCE(0);
        __builtin_amdgcn_s_barrier();        // all waves' A-reads retired
        MFMAQ(a1, b01, 4, 0);

        // ---- Ph4: stage (kt+2).A0,A1; Q4 = a1*b23
        if (kt + 2 < NT) { stageA(b, 0, kt + 2); stageA(b, 1, kt + 2); }
        MFMAQ(a1, b23, 4, 2);

        // ---- boundary: counted wait; retires through (kt+1).B1
        if (kt + 2 < NT)
            asm volatile("s_waitcnt vmcnt(6)\n\ts_barrier" ::: "memory");
        else if (kt + 1 < NT)
            asm volatile("s_waitcnt vmcnt(0)\n\ts_barrier" ::: "memory");
    }

    // epilogue: C/D layout col=lane&15, row=hi*4+reg
    const int cr = hi * 4, cc = lane & 15;
    if (ATOMIC) {
#pragma unroll
        for (int mi = 0; mi < 8; ++mi)
#pragma unroll
            for (int ni = 0; ni < 4; ++ni) {
                float* cp = C + (size_t)(bm * BM + wm * 128 + mi * 16 + cr) * OUT_F
                              + bn * BN + wn * 64 + ni * 16 + cc;
#pragma unroll
                for (int r = 0; r < 4; ++r)
                    unsafeAtomicAdd(cp + (size_t)r * OUT_F, acc[mi][ni][r]);
            }
    } else {
        __bf16* pp = P + (size_t)ks * BATCH * OUT_F;
#pragma unroll
        for (int mi = 0; mi < 8; ++mi)
#pragma unroll
            for (int ni = 0; ni < 4; ++ni) {
                __bf16* cp = pp + (size_t)(bm * BM + wm * 128 + mi * 16 + cr) * OUT_F
                                + bn * BN + wn * 64 + ni * 16 + cc;
#pragma unroll
                for (int r = 0; r < 4; ++r)
                    cp[(size_t)r * OUT_F] = (__bf16)acc[mi][ni][r];
            }
    }
}

extern "C" void kernel_launch(void* const* d_in, const int* in_sizes, int n_in,
                              void* d_out, int out_size, void* d_ws, size_t ws_size,
                              hipStream_t stream) {
    const float* x    = (const float*)d_in[0];
    const float* bw   = (const float*)d_in[1];
    const float* sw   = (const float*)d_in[2];
    const float* ss   = (const float*)d_in[3];

    const size_t wc_bytes   = (size_t)OUT_F * KC * 2;          // 18,874,368
    const size_t a_bytes    = (size_t)BATCH * KC * 2;          // 75,497,472
    const size_t part_bytes = 4ull * BATCH * OUT_F * 2;        // 33,554,432 (bf16)
    if (ws_size < wc_bytes + a_bytes) return;

    __bf16* Wc = (__bf16*)d_ws;
    __bf16* A  = (__bf16*)((char*)d_ws + wc_bytes);
    __bf16* P  = (__bf16*)((char*)d_ws + wc_bytes + a_bytes);

    prep_all<<<WC_BLK + A_BLK, 256, 0, stream>>>(bw, sw, ss, x, Wc, A);

    const int grid = (BATCH / BM) * (OUT_F / BN) * SPLITK;     // 256
    if (ws_size >= wc_bytes + a_bytes + part_bytes) {
        kan_gemm<false><<<grid, 512, 0, stream>>>(A, Wc, (float*)d_out, P);
        reduce_k<<<2048, 256, 0, stream>>>((float4*)d_out, (const __bf16*)P);
    } else {
        const int n4 = BATCH * OUT_F / 4;
        zero_out<<<n4 / 256, 256, 0, stream>>>((float4*)d_out, n4);
        kan_gemm<true><<<grid, 512, 0, stream>>>(A, Wc, (float*)d_out, P);
    }
}